// Round 8
// baseline (438.860 us; speedup 1.0000x reference)
//
#include <hip/hip_runtime.h>

#define BATCH 16
#define NPIX  4096
#define CCH   512
#define NSPLIT 8
#define KSPL  (NPIX / NSPLIT)   // 512
#define NUT   10                // upper-triangular 128x128 tile pairs of 4x4

using bf16x8   = __attribute__((ext_vector_type(8))) __bf16;
using floatx4  = __attribute__((ext_vector_type(4))) float;
using ushort8v = __attribute__((ext_vector_type(8))) unsigned short;
using ushort4v = __attribute__((ext_vector_type(4))) unsigned short;

static __device__ __forceinline__ unsigned short f2bf(float f) {
    unsigned u = __builtin_bit_cast(unsigned, f);
    unsigned r = 0x7fffu + ((u >> 16) & 1u);   // round-to-nearest-even
    return (unsigned short)((u + r) >> 16);
}
static __device__ __forceinline__ float bf2f(unsigned short v) {
    unsigned u = ((unsigned)v) << 16;
    return __builtin_bit_cast(float, u);
}
// async global->LDS, 16B per lane; LDS dest = wave-uniform base + lane*16
static __device__ __forceinline__ void gld16(const unsigned short* g, unsigned short* l) {
    __builtin_amdgcn_global_load_lds(
        (const __attribute__((address_space(1))) void*)g,
        (__attribute__((address_space(3))) void*)l,
        16, 0, 0);
}
// LDS byte offset of a __shared__ object (for asm ds_read)
#define LOFF(p) ((unsigned)(unsigned long long)(__attribute__((address_space(3))) const void*)(p))
// asm ds_read_b128: invisible to compiler AA -> no spurious vmcnt drains
#define DSR(d, a, o) asm volatile("ds_read_b128 %0, %1 offset:" o : "=v"(d) : "v"(a))

// ---------------------------------------------------------------------------
// Kernel 0: fp32 [b][n][c] -> bf16 Abf [b][n][c] AND bf16 AT [b][c][n]
// ---------------------------------------------------------------------------
__global__ __launch_bounds__(256) void k_cvt(const float* __restrict__ inp,
                                             unsigned short* __restrict__ Abf,
                                             unsigned short* __restrict__ AT) {
    __shared__ unsigned short sN[64 * 66];
    const int bn = blockIdx.x, bc = blockIdx.y, b = blockIdx.z;
    const int t  = threadIdx.x;
    const int n0 = bn * 64, c0 = bc * 64;
    const float* ip = inp + ((size_t)b * NPIX + n0) * CCH + c0;
    unsigned short* op = Abf + ((size_t)b * NPIX + n0) * CCH + c0;

#pragma unroll
    for (int r = 0; r < 2; ++r) {
        int n  = r * 32 + (t >> 3);
        int c8 = (t & 7) * 8;
        float4 v0 = *(const float4*)(ip + (size_t)n * CCH + c8);
        float4 v1 = *(const float4*)(ip + (size_t)n * CCH + c8 + 4);
        ushort8v w;
        w[0] = f2bf(v0.x); w[1] = f2bf(v0.y); w[2] = f2bf(v0.z); w[3] = f2bf(v0.w);
        w[4] = f2bf(v1.x); w[5] = f2bf(v1.y); w[6] = f2bf(v1.z); w[7] = f2bf(v1.w);
        *(ushort8v*)(op + (size_t)n * CCH + c8) = w;
        *(ushort8v*)&sN[n * 66 + c8] = w;
    }
    __syncthreads();

    const int cp = t >> 3;          // column pair 0..31
    const int ng = (t & 7) * 8;     // n group
    ushort8v o0, o1;
#pragma unroll
    for (int k = 0; k < 8; ++k) {
        unsigned d = *(const unsigned*)&sN[(ng + k) * 66 + cp * 2];
        o0[k] = (unsigned short)(d & 0xffffu);
        o1[k] = (unsigned short)(d >> 16);
    }
    unsigned short* tp = AT + ((size_t)b * CCH + c0) * NPIX + n0;
    *(ushort8v*)(tp + (size_t)(cp * 2)     * NPIX + ng) = o0;
    *(ushort8v*)(tp + (size_t)(cp * 2 + 1) * NPIX + ng) = o1;
}

// ---------------------------------------------------------------------------
// Shared macros: DOUBLE-buffered manual 2-phase pipeline (T3-minimum):
//   body t: stage(t+1)->buf[(t+1)&1]; asm ds_read+MFMA on buf[t&1];
//           s_waitcnt vmcnt(0); s_barrier.
// ---------------------------------------------------------------------------
#define GEMM_COMP(AADR, BADR)                                                  \
    {                                                                          \
        bf16x8 af[2], bv[8];                                                   \
        DSR(af[0], (AADR), "0");    DSR(af[1], (AADR), "1024");                \
        DSR(bv[0], (BADR), "0");    DSR(bv[1], (BADR), "1024");                \
        DSR(bv[2], (BADR), "2048"); DSR(bv[3], (BADR), "3072");                \
        DSR(bv[4], (BADR), "4096"); DSR(bv[5], (BADR), "5120");                \
        DSR(bv[6], (BADR), "6144"); DSR(bv[7], (BADR), "7168");                \
        asm volatile("s_waitcnt lgkmcnt(0)" ::: "memory");                     \
        __builtin_amdgcn_sched_barrier(0);                                     \
        _Pragma("unroll")                                                      \
        for (int tm = 0; tm < 2; ++tm)                                         \
            _Pragma("unroll")                                                  \
            for (int tn = 0; tn < 8; ++tn)                                     \
                acc[tm][tn] = __builtin_amdgcn_mfma_f32_16x16x32_bf16(         \
                    af[tm], bv[tn], acc[tm][tn], 0, 0, 0);                     \
    }

#define GEMM_WAIT0                                                             \
    asm volatile("s_waitcnt vmcnt(0)" ::: "memory");                           \
    __builtin_amdgcn_s_barrier();

// ---------------------------------------------------------------------------
// Kernel 1: upper-triangular tile pairs of S = A^T A, split-K = 8.
// 128^2 tile, 4 waves, double-buffer.
// Sp tile layout is MFMA-register-packed bf16:
//   elem (row,col) at (((row>>4)*8 + (col>>4))*64 + (row>>2 & 3)*16 + (col&15))*4 + (row&3)
// ---------------------------------------------------------------------------
__global__ __launch_bounds__(256) void k_ata(const unsigned short* __restrict__ AT,
                                             unsigned short* __restrict__ Sp) {
    __shared__ unsigned short sA0[128 * 32];
    __shared__ unsigned short sA1[128 * 32];
    __shared__ unsigned short sB0[128 * 32];
    __shared__ unsigned short sB1[128 * 32];
    const int u = blockIdx.x, s = blockIdx.y, b = blockIdx.z;
    const int ti = (u < 4) ? 0 : (u < 7) ? 1 : (u < 9) ? 2 : 3;
    const int u0 = ti * 5 - (ti * (ti + 1)) / 2;   // first u at tj==ti
    const int tj = ti + (u - u0);
    const unsigned short* pa = AT + ((size_t)b * CCH + ti * 128) * NPIX + s * KSPL;
    const unsigned short* pb = AT + ((size_t)b * CCH + tj * 128) * NPIX + s * KSPL;
    const int tid = threadIdx.x, lane = tid & 63, wave = tid >> 6;
    const int lrow = lane >> 2;
    const int lk   = (lane & 3) * 8;
    const int kq   = (lane >> 4) * 8;

    const unsigned aoff = (unsigned)((wave * 32 + (lane & 15)) * 64 + kq * 2);
    const unsigned boff = (unsigned)((lane & 15) * 64 + kq * 2);
    const unsigned aA0 = LOFF(sA0) + aoff, aA1 = LOFF(sA1) + aoff;
    const unsigned aB0 = LOFF(sB0) + boff, aB1 = LOFF(sB1) + boff;

    floatx4 acc[2][8];
#pragma unroll
    for (int tm = 0; tm < 2; ++tm)
#pragma unroll
        for (int tn = 0; tn < 8; ++tn)
            acc[tm][tn] = floatx4{0.f, 0.f, 0.f, 0.f};

#define STG(DA, DB, K0)                                                        \
    {                                                                          \
        _Pragma("unroll")                                                      \
        for (int i = 0; i < 2; ++i) {                                          \
            const int r = wave * 32 + i * 16;                                  \
            gld16(pa + (size_t)(r + lrow) * NPIX + (K0) + lk, &DA[r * 32]);    \
            gld16(pb + (size_t)(r + lrow) * NPIX + (K0) + lk, &DB[r * 32]);    \
        }                                                                      \
    }
#define BODYS(NA, NB, K2, CA, CB) STG(NA, NB, K2) GEMM_COMP(CA, CB) GEMM_WAIT0

    // prologue: stage k-tile 0 into buffer 0
    STG(sA0, sB0, 0)
    GEMM_WAIT0

    BODYS(sA1, sB1,  32, aA0, aB0)   // t=0
    BODYS(sA0, sB0,  64, aA1, aB1)   // t=1
    BODYS(sA1, sB1,  96, aA0, aB0)   // t=2
    BODYS(sA0, sB0, 128, aA1, aB1)   // t=3
    BODYS(sA1, sB1, 160, aA0, aB0)   // t=4
    BODYS(sA0, sB0, 192, aA1, aB1)   // t=5
    BODYS(sA1, sB1, 224, aA0, aB0)   // t=6
    BODYS(sA0, sB0, 256, aA1, aB1)   // t=7
    BODYS(sA1, sB1, 288, aA0, aB0)   // t=8
    BODYS(sA0, sB0, 320, aA1, aB1)   // t=9
    BODYS(sA1, sB1, 352, aA0, aB0)   // t=10
    BODYS(sA0, sB0, 384, aA1, aB1)   // t=11
    BODYS(sA1, sB1, 416, aA0, aB0)   // t=12
    BODYS(sA0, sB0, 448, aA1, aB1)   // t=13
    BODYS(sA1, sB1, 480, aA0, aB0)   // t=14
    GEMM_COMP(aA1, aB1)              // t=15
#undef BODYS
#undef STG

    // packed epilogue: 8B/lane fully-coalesced stores
    unsigned short* Tb = Sp + ((((size_t)s * BATCH + b) * NUT + u) << 14);
#pragma unroll
    for (int tm = 0; tm < 2; ++tm)
#pragma unroll
        for (int tn = 0; tn < 8; ++tn) {
            ushort4v w;
#pragma unroll
            for (int r = 0; r < 4; ++r) w[r] = f2bf(acc[tm][tn][r]);
            *(ushort4v*)&Tb[((((wave * 2 + tm) * 8 + tn) * 64) + lane) * 4] = w;
        }
}

// ---------------------------------------------------------------------------
// Kernel 2: gather 8 bf16 split-partials, fp32 sum, row softmax -> P bf16.
// ---------------------------------------------------------------------------
__global__ __launch_bounds__(256) void k_softmax(const unsigned short* __restrict__ Sp,
                                                 unsigned short* __restrict__ P) {
    __shared__ float red[6];
    const int row = blockIdx.x;            // b*512 + i
    const int b = row >> 9, i = row & 511;
    const int tid = threadIdx.x, lane = tid & 63, wave = tid >> 6;
    const size_t sstr = (size_t)BATCH * NUT * 16384;   // split stride (shorts)

    float x[2];
#pragma unroll
    for (int e = 0; e < 2; ++e) {
        const int j  = tid + e * 256;
        const int ti = i >> 7, tj = j >> 7;
        const int il = i & 127, jl = j & 127;
        const bool sw = ti > tj;
        const int a  = sw ? tj : ti;
        const int cm = sw ? ti : tj;
        const int u  = a * 4 + cm - ((a * (a + 1)) >> 1);
        const int rr = sw ? jl : il;
        const int cc = sw ? il : jl;
        const int off = ((((rr >> 4) * 8 + (cc >> 4)) * 64) +
                         ((rr >> 2) & 3) * 16 + (cc & 15)) * 4 + (rr & 3);
        const size_t base = (((size_t)b * NUT + u) << 14) + off;
        float v = 0.f;
#pragma unroll
        for (int s = 0; s < NSPLIT; ++s) v += bf2f(Sp[base + s * sstr]);
        x[e] = v;
    }

    float m = fmaxf(x[0], x[1]);
#pragma unroll
    for (int o = 32; o; o >>= 1) m = fmaxf(m, __shfl_xor(m, o, 64));
    if (lane == 0) red[wave] = m;
    __syncthreads();
    if (tid == 0) red[4] = fmaxf(fmaxf(red[0], red[1]), fmaxf(red[2], red[3]));
    __syncthreads();
    m = red[4];

    float e0 = __expf(x[0] - m), e1 = __expf(x[1] - m);
    float sum = e0 + e1;
#pragma unroll
    for (int o = 32; o; o >>= 1) sum += __shfl_xor(sum, o, 64);
    if (lane == 0) red[wave] = sum;
    __syncthreads();
    if (tid == 0) red[5] = red[0] + red[1] + red[2] + red[3];
    __syncthreads();
    float inv = 1.0f / red[5];

    P[(size_t)row * CCH + tid]       = f2bf(e0 * inv);
    P[(size_t)row * CCH + tid + 256] = f2bf(e1 * inv);
}

// ---------------------------------------------------------------------------
// Kernel 3: out[b][n][i] = gamma * sum_j P[b][i][j]*Abf[b][n][j] + inp[b][n][i]
// 256x256 tile, 8 waves (2x4), per-wave 128x64 output, acc[8][4] floatx4.
// Double-buffered 2-phase K-loop + VECTORIZED LDS-REPACK EPILOGUE:
// acc round-trips through 32KB LDS in 8 m-chunks so the residual-add runs as
// lane-contiguous dwordx4 (32 loads + 32 stores/thread vs 128 scalar each).
// ---------------------------------------------------------------------------
__global__ __launch_bounds__(512) void k_av(const unsigned short* __restrict__ Abf,
                                            const unsigned short* __restrict__ P,
                                            const float* __restrict__ inp,
                                            const float* __restrict__ gamma,
                                            float* __restrict__ out) {
    __shared__ unsigned short sA0[256 * 32];
    __shared__ unsigned short sA1[256 * 32];
    __shared__ unsigned short sB0[256 * 32];
    __shared__ unsigned short sB1[256 * 32];
    __shared__ float sEp[8192];              // 32 KB epilogue repack buffer
    const int bn = blockIdx.x, bi = blockIdx.y, b = blockIdx.z;
    const unsigned short* pa = Abf + ((size_t)b * NPIX + bn * 256) * CCH;
    const unsigned short* pb = P + ((size_t)b * CCH + bi * 256) * CCH;
    const int tid = threadIdx.x, lane = tid & 63, wave = tid >> 6;
    const int wr = wave >> 2;        // 0..1  (row band of 128)
    const int wc = wave & 3;         // 0..3  (col band of 64)
    const int lrow = lane >> 2;
    const int lk   = (lane & 3) * 8;
    const int kq   = (lane >> 4) * 8;
    const float g = gamma[0];

    const unsigned aoff = (unsigned)((wr * 128 + (lane & 15)) * 64 + kq * 2);
    const unsigned boff = (unsigned)((wc * 64 + (lane & 15)) * 64 + kq * 2);
    const unsigned aA0 = LOFF(sA0) + aoff, aA1 = LOFF(sA1) + aoff;
    const unsigned aB0 = LOFF(sB0) + boff, aB1 = LOFF(sB1) + boff;

    floatx4 acc[8][4];
#pragma unroll
    for (int m = 0; m < 8; ++m)
#pragma unroll
        for (int n = 0; n < 4; ++n)
            acc[m][n] = floatx4{0.f, 0.f, 0.f, 0.f};

#define STG(DA, DB, K0)                                                        \
    {                                                                          \
        _Pragma("unroll")                                                      \
        for (int i = 0; i < 2; ++i) {                                          \
            const int r = (wave * 2 + i) * 16;                                 \
            gld16(pa + (size_t)(r + lrow) * CCH + (K0) + lk, &DA[r * 32]);     \
            gld16(pb + (size_t)(r + lrow) * CCH + (K0) + lk, &DB[r * 32]);     \
        }                                                                      \
    }
#define AV_COMP(AADR, BADR)                                                    \
    {                                                                          \
        bf16x8 af[8], bv[4];                                                   \
        DSR(af[0], (AADR), "0");    DSR(af[1], (AADR), "1024");                \
        DSR(af[2], (AADR), "2048"); DSR(af[3], (AADR), "3072");                \
        DSR(af[4], (AADR), "4096"); DSR(af[5], (AADR), "5120");                \
        DSR(af[6], (AADR), "6144"); DSR(af[7], (AADR), "7168");                \
        DSR(bv[0], (BADR), "0");    DSR(bv[1], (BADR), "1024");                \
        DSR(bv[2], (BADR), "2048"); DSR(bv[3], (BADR), "3072");                \
        asm volatile("s_waitcnt lgkmcnt(0)" ::: "memory");                     \
        __builtin_amdgcn_sched_barrier(0);                                     \
        _Pragma("unroll")                                                      \
        for (int m = 0; m < 8; ++m)                                            \
            _Pragma("unroll")                                                  \
            for (int n = 0; n < 4; ++n)                                        \
                acc[m][n] = __builtin_amdgcn_mfma_f32_16x16x32_bf16(           \
                    af[m], bv[n], acc[m][n], 0, 0, 0);                         \
    }
#define BODYS(NA, NB, K2, CA, CB) STG(NA, NB, K2) AV_COMP(CA, CB) GEMM_WAIT0

    // prologue: stage k-tile 0 into buffer 0
    STG(sA0, sB0, 0)
    GEMM_WAIT0

    BODYS(sA1, sB1,  32, aA0, aB0)   // t=0
    BODYS(sA0, sB0,  64, aA1, aB1)   // t=1
    BODYS(sA1, sB1,  96, aA0, aB0)   // t=2
    BODYS(sA0, sB0, 128, aA1, aB1)   // t=3
    BODYS(sA1, sB1, 160, aA0, aB0)   // t=4
    BODYS(sA0, sB0, 192, aA1, aB1)   // t=5
    BODYS(sA1, sB1, 224, aA0, aB0)   // t=6
    BODYS(sA0, sB0, 256, aA1, aB1)   // t=7
    BODYS(sA1, sB1, 288, aA0, aB0)   // t=8
    BODYS(sA0, sB0, 320, aA1, aB1)   // t=9
    BODYS(sA1, sB1, 352, aA0, aB0)   // t=10
    BODYS(sA0, sB0, 384, aA1, aB1)   // t=11
    BODYS(sA1, sB1, 416, aA0, aB0)   // t=12
    BODYS(sA0, sB0, 448, aA1, aB1)   // t=13
    BODYS(sA1, sB1, 480, aA0, aB0)   // t=14
    AV_COMP(aA1, aB1)                // t=15
#undef BODYS
#undef AV_COMP
#undef STG

    // ---- vectorized epilogue: 8 chunks of 32 KB (2 bands x 16 rows x 256 cols)
    float* Ob = out + ((size_t)b * NPIX + bn * 256) * CCH + bi * 256;
    const float* Ib = inp + ((size_t)b * NPIX + bn * 256) * CCH + bi * 256;
#pragma unroll 1
    for (int m = 0; m < 8; ++m) {
        __syncthreads();   // LDS quiescent (K-loop bufs / previous chunk)
        // scatter this chunk's acc into sEp[band][row16][col256]
#pragma unroll
        for (int n = 0; n < 4; ++n)
#pragma unroll
            for (int r = 0; r < 4; ++r) {
                int rowin = (lane >> 4) * 4 + r;
                int col   = wc * 64 + n * 16 + (lane & 15);
                sEp[wr * 4096 + rowin * 256 + col] = acc[m][n][r];
            }
        __syncthreads();
        // contiguous read-back + dwordx4 residual-add
#pragma unroll
        for (int q = 0; q < 4; ++q) {
            float4 s4 = *(const float4*)&sEp[q * 2048 + tid * 4];
            int band  = q >> 1;
            int rowin = (q & 1) * 8 + (tid >> 6);
            int grow  = band * 128 + m * 16 + rowin;
            int gcol  = (tid & 63) * 4;
            size_t o  = (size_t)grow * CCH + gcol;
            float4 i4 = *(const float4*)(Ib + o);
            float4 o4;
            o4.x = g * s4.x + i4.x; o4.y = g * s4.y + i4.y;
            o4.z = g * s4.z + i4.z; o4.w = g * s4.w + i4.w;
            *(float4*)(Ob + o) = o4;
        }
    }
}

// ---------------------------------------------------------------------------
extern "C" void kernel_launch(void* const* d_in, const int* in_sizes, int n_in,
                              void* d_out, int out_size, void* d_ws, size_t ws_size,
                              hipStream_t stream) {
    const float* inp   = (const float*)d_in[0];
    const float* gamma = (const float*)d_in[1];
    float* out = (float*)d_out;

    // workspace: Abf 64 MiB | AT 64 MiB | Sp 40 MiB | P 8 MiB  (~176.5 MiB)
    char* ws = (char*)d_ws;
    unsigned short* Abf = (unsigned short*)ws;
    unsigned short* AT  = (unsigned short*)(ws + (size_t)67108864);
    unsigned short* Sp  = (unsigned short*)(ws + (size_t)134217728);
    unsigned short* P   = (unsigned short*)(ws + (size_t)134217728 + 41943040);

    k_cvt<<<dim3(NPIX / 64, CCH / 64, BATCH), 256, 0, stream>>>(inp, Abf, AT);
    k_ata<<<dim3(NUT, NSPLIT, BATCH), 256, 0, stream>>>(AT, Sp);
    k_softmax<<<BATCH * CCH, 256, 0, stream>>>(Sp, P);
    k_av<<<dim3(NPIX / 256, CCH / 256, BATCH), 512, 0, stream>>>(Abf, P, inp, gamma, out);
}

// Round 10
// 380.938 us; speedup vs baseline: 1.1521x; 1.1521x over previous
//
#include <hip/hip_runtime.h>

#define BATCH 16
#define NPIX  4096
#define CCH   512
#define NSPLIT 8
#define KSPL  (NPIX / NSPLIT)   // 512
#define NUT   10                // upper-triangular 128x128 tile pairs of 4x4

using bf16x8   = __attribute__((ext_vector_type(8))) __bf16;
using floatx4  = __attribute__((ext_vector_type(4))) float;
using ushort8v = __attribute__((ext_vector_type(8))) unsigned short;
using ushort4v = __attribute__((ext_vector_type(4))) unsigned short;

static __device__ __forceinline__ unsigned short f2bf(float f) {
    unsigned u = __builtin_bit_cast(unsigned, f);
    unsigned r = 0x7fffu + ((u >> 16) & 1u);   // round-to-nearest-even
    return (unsigned short)((u + r) >> 16);
}
static __device__ __forceinline__ float bf2f(unsigned short v) {
    unsigned u = ((unsigned)v) << 16;
    return __builtin_bit_cast(float, u);
}
// async global->LDS, 16B per lane; LDS dest = wave-uniform base + lane*16
static __device__ __forceinline__ void gld16(const unsigned short* g, unsigned short* l) {
    __builtin_amdgcn_global_load_lds(
        (const __attribute__((address_space(1))) void*)g,
        (__attribute__((address_space(3))) void*)l,
        16, 0, 0);
}
// LDS byte offset of a __shared__ object (for asm ds_read)
#define LOFF(p) ((unsigned)(unsigned long long)(__attribute__((address_space(3))) const void*)(p))
// asm ds_read_b128: invisible to compiler AA -> no spurious vmcnt drains
#define DSR(d, a, o) asm volatile("ds_read_b128 %0, %1 offset:" o : "=v"(d) : "v"(a))

// ---------------------------------------------------------------------------
// Kernel 0: fp32 [b][n][c] -> bf16 Abf [b][n][c] AND bf16 AT [b][c][n]
// ---------------------------------------------------------------------------
__global__ __launch_bounds__(256) void k_cvt(const float* __restrict__ inp,
                                             unsigned short* __restrict__ Abf,
                                             unsigned short* __restrict__ AT) {
    __shared__ unsigned short sN[64 * 66];
    const int bn = blockIdx.x, bc = blockIdx.y, b = blockIdx.z;
    const int t  = threadIdx.x;
    const int n0 = bn * 64, c0 = bc * 64;
    const float* ip = inp + ((size_t)b * NPIX + n0) * CCH + c0;
    unsigned short* op = Abf + ((size_t)b * NPIX + n0) * CCH + c0;

#pragma unroll
    for (int r = 0; r < 2; ++r) {
        int n  = r * 32 + (t >> 3);
        int c8 = (t & 7) * 8;
        float4 v0 = *(const float4*)(ip + (size_t)n * CCH + c8);
        float4 v1 = *(const float4*)(ip + (size_t)n * CCH + c8 + 4);
        ushort8v w;
        w[0] = f2bf(v0.x); w[1] = f2bf(v0.y); w[2] = f2bf(v0.z); w[3] = f2bf(v0.w);
        w[4] = f2bf(v1.x); w[5] = f2bf(v1.y); w[6] = f2bf(v1.z); w[7] = f2bf(v1.w);
        *(ushort8v*)(op + (size_t)n * CCH + c8) = w;
        *(ushort8v*)&sN[n * 66 + c8] = w;
    }
    __syncthreads();

    const int cp = t >> 3;          // column pair 0..31
    const int ng = (t & 7) * 8;     // n group
    ushort8v o0, o1;
#pragma unroll
    for (int k = 0; k < 8; ++k) {
        unsigned d = *(const unsigned*)&sN[(ng + k) * 66 + cp * 2];
        o0[k] = (unsigned short)(d & 0xffffu);
        o1[k] = (unsigned short)(d >> 16);
    }
    unsigned short* tp = AT + ((size_t)b * CCH + c0) * NPIX + n0;
    *(ushort8v*)(tp + (size_t)(cp * 2)     * NPIX + ng) = o0;
    *(ushort8v*)(tp + (size_t)(cp * 2 + 1) * NPIX + ng) = o1;
}

// ---------------------------------------------------------------------------
// Shared GEMM macros.
// ---------------------------------------------------------------------------
#define GEMM_COMP(AADR, BADR)                                                  \
    {                                                                          \
        bf16x8 af[2], bv[8];                                                   \
        DSR(af[0], (AADR), "0");    DSR(af[1], (AADR), "1024");                \
        DSR(bv[0], (BADR), "0");    DSR(bv[1], (BADR), "1024");                \
        DSR(bv[2], (BADR), "2048"); DSR(bv[3], (BADR), "3072");                \
        DSR(bv[4], (BADR), "4096"); DSR(bv[5], (BADR), "5120");                \
        DSR(bv[6], (BADR), "6144"); DSR(bv[7], (BADR), "7168");                \
        asm volatile("s_waitcnt lgkmcnt(0)" ::: "memory");                     \
        __builtin_amdgcn_sched_barrier(0);                                     \
        _Pragma("unroll")                                                      \
        for (int tm = 0; tm < 2; ++tm)                                         \
            _Pragma("unroll")                                                  \
            for (int tn = 0; tn < 8; ++tn)                                     \
                acc[tm][tn] = __builtin_amdgcn_mfma_f32_16x16x32_bf16(         \
                    af[tm], bv[tn], acc[tm][tn], 0, 0, 0);                     \
    }

#define GEMM_WAIT4                                                             \
    asm volatile("s_waitcnt vmcnt(4)" ::: "memory");                           \
    __builtin_amdgcn_s_barrier();
#define GEMM_WAIT0                                                             \
    asm volatile("s_waitcnt vmcnt(0)" ::: "memory");                           \
    __builtin_amdgcn_s_barrier();

// ---------------------------------------------------------------------------
// Kernel 1: upper-triangular tile pairs of S = A^T A, split-K = 8.
// Triple-buffered depth-2 counted-vmcnt pipeline (round-3 form, best total).
// Sp tile layout is MFMA-register-packed bf16:
//   elem (row,col) at (((row>>4)*8 + (col>>4))*64 + (row>>2 & 3)*16 + (col&15))*4 + (row&3)
// ---------------------------------------------------------------------------
__global__ __launch_bounds__(256) void k_ata(const unsigned short* __restrict__ AT,
                                             unsigned short* __restrict__ Sp) {
    __shared__ unsigned short sA0[128 * 32];
    __shared__ unsigned short sA1[128 * 32];
    __shared__ unsigned short sA2[128 * 32];
    __shared__ unsigned short sB0[128 * 32];
    __shared__ unsigned short sB1[128 * 32];
    __shared__ unsigned short sB2[128 * 32];
    const int u = blockIdx.x, s = blockIdx.y, b = blockIdx.z;
    const int ti = (u < 4) ? 0 : (u < 7) ? 1 : (u < 9) ? 2 : 3;
    const int u0 = ti * 5 - (ti * (ti + 1)) / 2;   // first u at tj==ti
    const int tj = ti + (u - u0);
    const unsigned short* pa = AT + ((size_t)b * CCH + ti * 128) * NPIX + s * KSPL;
    const unsigned short* pb = AT + ((size_t)b * CCH + tj * 128) * NPIX + s * KSPL;
    const int tid = threadIdx.x, lane = tid & 63, wave = tid >> 6;
    const int lrow = lane >> 2;
    const int lk   = (lane & 3) * 8;
    const int kq   = (lane >> 4) * 8;

    const unsigned aoff = (unsigned)((wave * 32 + (lane & 15)) * 64 + kq * 2);
    const unsigned boff = (unsigned)((lane & 15) * 64 + kq * 2);
    const unsigned aA0 = LOFF(sA0) + aoff, aA1 = LOFF(sA1) + aoff, aA2 = LOFF(sA2) + aoff;
    const unsigned aB0 = LOFF(sB0) + boff, aB1 = LOFF(sB1) + boff, aB2 = LOFF(sB2) + boff;

    floatx4 acc[2][8];
#pragma unroll
    for (int tm = 0; tm < 2; ++tm)
#pragma unroll
        for (int tn = 0; tn < 8; ++tn)
            acc[tm][tn] = floatx4{0.f, 0.f, 0.f, 0.f};

#define STG(DA, DB, K0)                                                        \
    {                                                                          \
        _Pragma("unroll")                                                      \
        for (int i = 0; i < 2; ++i) {                                          \
            const int r = wave * 32 + i * 16;                                  \
            gld16(pa + (size_t)(r + lrow) * NPIX + (K0) + lk, &DA[r * 32]);    \
            gld16(pb + (size_t)(r + lrow) * NPIX + (K0) + lk, &DB[r * 32]);    \
        }                                                                      \
    }
#define BODYS(NA, NB, K2, CA, CB) STG(NA, NB, K2) GEMM_COMP(CA, CB) GEMM_WAIT4

    STG(sA0, sB0, 0)
    STG(sA1, sB1, 32)
    GEMM_WAIT4

    BODYS(sA2, sB2,  64, aA0, aB0)   // t=0
    BODYS(sA0, sB0,  96, aA1, aB1)   // t=1
    BODYS(sA1, sB1, 128, aA2, aB2)   // t=2
    BODYS(sA2, sB2, 160, aA0, aB0)   // t=3
    BODYS(sA0, sB0, 192, aA1, aB1)   // t=4
    BODYS(sA1, sB1, 224, aA2, aB2)   // t=5
    BODYS(sA2, sB2, 256, aA0, aB0)   // t=6
    BODYS(sA0, sB0, 288, aA1, aB1)   // t=7
    BODYS(sA1, sB1, 320, aA2, aB2)   // t=8
    BODYS(sA2, sB2, 352, aA0, aB0)   // t=9
    BODYS(sA0, sB0, 384, aA1, aB1)   // t=10
    BODYS(sA1, sB1, 416, aA2, aB2)   // t=11
    BODYS(sA2, sB2, 448, aA0, aB0)   // t=12
    BODYS(sA0, sB0, 480, aA1, aB1)   // t=13
    GEMM_COMP(aA2, aB2) GEMM_WAIT0   // t=14
    GEMM_COMP(aA0, aB0)              // t=15
#undef BODYS
#undef STG

    // packed epilogue: 8B/lane fully-coalesced stores
    unsigned short* Tb = Sp + ((((size_t)s * BATCH + b) * NUT + u) << 14);
#pragma unroll
    for (int tm = 0; tm < 2; ++tm)
#pragma unroll
        for (int tn = 0; tn < 8; ++tn) {
            ushort4v w;
#pragma unroll
            for (int r = 0; r < 4; ++r) w[r] = f2bf(acc[tm][tn][r]);
            *(ushort4v*)&Tb[((((wave * 2 + tm) * 8 + tn) * 64) + lane) * 4] = w;
        }
}

// ---------------------------------------------------------------------------
// Kernel 2: quad-row softmax. Block handles 4 consecutive rows (same rr>>2
// group), exploiting packed layout's rr&3-contiguity:
//  direct tiles (ti<=tj): one 8B ushort4 load yields all 4 rows
//  mirrored tiles: 4 shorts at stride 4 (32B window)
// Per-thread 2 column slots x 4 rows; reductions 4-row-batched.
// ---------------------------------------------------------------------------
__global__ __launch_bounds__(256) void k_softmax(const unsigned short* __restrict__ Sp,
                                                 unsigned short* __restrict__ P) {
    __shared__ float red[4][4];
    const int blk = blockIdx.x;          // b*128 + r0
    const int b = blk >> 7, r0 = blk & 127;
    const int i4  = r0 * 4;              // first row of quad (0..508)
    const int ti  = i4 >> 7;
    const int il0 = i4 & 127;            // quad-aligned in-tile row
    const int tid = threadIdx.x, lane = tid & 63, wave = tid >> 6;
    const size_t sstr = (size_t)BATCH * NUT * 16384;   // split stride (shorts)

    float x[2][4];
#pragma unroll
    for (int e = 0; e < 2; ++e)
#pragma unroll
        for (int k = 0; k < 4; ++k) x[e][k] = 0.f;

#pragma unroll
    for (int e = 0; e < 2; ++e) {
        const int j  = tid + e * 256;
        const int tj = j >> 7, jl = j & 127;
        if (ti <= tj) {
            const int u = ti * 4 + tj - ((ti * (ti + 1)) >> 1);
            const int off = (((il0 >> 4) * 8 + (jl >> 4)) * 64 +
                             ((il0 >> 2) & 3) * 16 + (jl & 15)) * 4;   // rr&3=k
            const size_t base = (((size_t)b * NUT + u) << 14) + off;
#pragma unroll
            for (int s = 0; s < NSPLIT; ++s) {
                ushort4v v = *(const ushort4v*)&Sp[base + s * sstr];
                x[e][0] += bf2f(v[0]); x[e][1] += bf2f(v[1]);
                x[e][2] += bf2f(v[2]); x[e][3] += bf2f(v[3]);
            }
        } else {
            const int u = tj * 4 + ti - ((tj * (tj + 1)) >> 1);
            const int off = ((((jl >> 4) * 8 + (il0 >> 4)) * 64 +
                              ((jl >> 2) & 3) * 16 + (il0 & 15)) * 4) + (jl & 3);
            const size_t base = (((size_t)b * NUT + u) << 14) + off;
#pragma unroll
            for (int s = 0; s < NSPLIT; ++s) {
                const unsigned short* p = &Sp[base + s * sstr];
                x[e][0] += bf2f(p[0]);  x[e][1] += bf2f(p[4]);
                x[e][2] += bf2f(p[8]);  x[e][3] += bf2f(p[12]);
            }
        }
    }

    // per-row max (4 rows batched)
#pragma unroll
    for (int k = 0; k < 4; ++k) {
        float m = fmaxf(x[0][k], x[1][k]);
#pragma unroll
        for (int o = 32; o; o >>= 1) m = fmaxf(m, __shfl_xor(m, o, 64));
        if (lane == 0) red[wave][k] = m;
    }
    __syncthreads();
    float m4[4];
#pragma unroll
    for (int k = 0; k < 4; ++k)
        m4[k] = fmaxf(fmaxf(red[0][k], red[1][k]), fmaxf(red[2][k], red[3][k]));
    __syncthreads();

    float e0[4], e1[4];
#pragma unroll
    for (int k = 0; k < 4; ++k) {
        e0[k] = __expf(x[0][k] - m4[k]);
        e1[k] = __expf(x[1][k] - m4[k]);
        float s = e0[k] + e1[k];
#pragma unroll
        for (int o = 32; o; o >>= 1) s += __shfl_xor(s, o, 64);
        if (lane == 0) red[wave][k] = s;
    }
    __syncthreads();
#pragma unroll
    for (int k = 0; k < 4; ++k) {
        float inv = 1.0f / (red[0][k] + red[1][k] + red[2][k] + red[3][k]);
        const size_t rowo = ((size_t)(b * 512 + i4 + k)) * CCH;
        P[rowo + tid]       = f2bf(e0[k] * inv);
        P[rowo + tid + 256] = f2bf(e1[k] * inv);
    }
}

// ---------------------------------------------------------------------------
// Kernel 3: out[b][n][i] = gamma * sum_j P[b][i][j]*Abf[b][n][j] + inp[b][n][i]
// 256x256 tile, 8 waves (2x4), per-wave 128x64 output, acc[8][4] floatx4.
// Double-buffer 2-phase manual pipeline (round-7 form, best measured 83.5us).
// ---------------------------------------------------------------------------
__global__ __launch_bounds__(512) void k_av(const unsigned short* __restrict__ Abf,
                                            const unsigned short* __restrict__ P,
                                            const float* __restrict__ inp,
                                            const float* __restrict__ gamma,
                                            float* __restrict__ out) {
    __shared__ unsigned short sA0[256 * 32];
    __shared__ unsigned short sA1[256 * 32];
    __shared__ unsigned short sB0[256 * 32];
    __shared__ unsigned short sB1[256 * 32];
    const int bn = blockIdx.x, bi = blockIdx.y, b = blockIdx.z;
    const unsigned short* pa = Abf + ((size_t)b * NPIX + bn * 256) * CCH;
    const unsigned short* pb = P + ((size_t)b * CCH + bi * 256) * CCH;
    const int tid = threadIdx.x, lane = tid & 63, wave = tid >> 6;
    const int wr = wave >> 2;        // 0..1  (row band of 128)
    const int wc = wave & 3;         // 0..3  (col band of 64)
    const int lrow = lane >> 2;
    const int lk   = (lane & 3) * 8;
    const int kq   = (lane >> 4) * 8;
    const float g = gamma[0];

    const unsigned aoff = (unsigned)((wr * 128 + (lane & 15)) * 64 + kq * 2);
    const unsigned boff = (unsigned)((wc * 64 + (lane & 15)) * 64 + kq * 2);
    const unsigned aA0 = LOFF(sA0) + aoff, aA1 = LOFF(sA1) + aoff;
    const unsigned aB0 = LOFF(sB0) + boff, aB1 = LOFF(sB1) + boff;

    floatx4 acc[8][4];
#pragma unroll
    for (int m = 0; m < 8; ++m)
#pragma unroll
        for (int n = 0; n < 4; ++n)
            acc[m][n] = floatx4{0.f, 0.f, 0.f, 0.f};

#define STG(DA, DB, K0)                                                        \
    {                                                                          \
        _Pragma("unroll")                                                      \
        for (int i = 0; i < 2; ++i) {                                          \
            const int r = (wave * 2 + i) * 16;                                 \
            gld16(pa + (size_t)(r + lrow) * CCH + (K0) + lk, &DA[r * 32]);     \
            gld16(pb + (size_t)(r + lrow) * CCH + (K0) + lk, &DB[r * 32]);     \
        }                                                                      \
    }
#define AV_COMP(AADR, BADR)                                                    \
    {                                                                          \
        bf16x8 af[8], bv[4];                                                   \
        DSR(af[0], (AADR), "0");    DSR(af[1], (AADR), "1024");                \
        DSR(af[2], (AADR), "2048"); DSR(af[3], (AADR), "3072");                \
        DSR(af[4], (AADR), "4096"); DSR(af[5], (AADR), "5120");                \
        DSR(af[6], (AADR), "6144"); DSR(af[7], (AADR), "7168");                \
        DSR(bv[0], (BADR), "0");    DSR(bv[1], (BADR), "1024");                \
        DSR(bv[2], (BADR), "2048"); DSR(bv[3], (BADR), "3072");                \
        asm volatile("s_waitcnt lgkmcnt(0)" ::: "memory");                     \
        __builtin_amdgcn_sched_barrier(0);                                     \
        _Pragma("unroll")                                                      \
        for (int m = 0; m < 8; ++m)                                            \
            _Pragma("unroll")                                                  \
            for (int n = 0; n < 4; ++n)                                        \
                acc[m][n] = __builtin_amdgcn_mfma_f32_16x16x32_bf16(           \
                    af[m], bv[n], acc[m][n], 0, 0, 0);                         \
    }
#define BODYS(NA, NB, K2, CA, CB) STG(NA, NB, K2) AV_COMP(CA, CB) GEMM_WAIT0

    // prologue: stage k-tile 0 into buffer 0
    STG(sA0, sB0, 0)
    GEMM_WAIT0

    BODYS(sA1, sB1,  32, aA0, aB0)   // t=0
    BODYS(sA0, sB0,  64, aA1, aB1)   // t=1
    BODYS(sA1, sB1,  96, aA0, aB0)   // t=2
    BODYS(sA0, sB0, 128, aA1, aB1)   // t=3
    BODYS(sA1, sB1, 160, aA0, aB0)   // t=4
    BODYS(sA0, sB0, 192, aA1, aB1)   // t=5
    BODYS(sA1, sB1, 224, aA0, aB0)   // t=6
    BODYS(sA0, sB0, 256, aA1, aB1)   // t=7
    BODYS(sA1, sB1, 288, aA0, aB0)   // t=8
    BODYS(sA0, sB0, 320, aA1, aB1)   // t=9
    BODYS(sA1, sB1, 352, aA0, aB0)   // t=10
    BODYS(sA0, sB0, 384, aA1, aB1)   // t=11
    BODYS(sA1, sB1, 416, aA0, aB0)   // t=12
    BODYS(sA0, sB0, 448, aA1, aB1)   // t=13
    BODYS(sA1, sB1, 480, aA0, aB0)   // t=14
    AV_COMP(aA1, aB1)                // t=15
#undef BODYS
#undef AV_COMP
#undef STG

    float* Ob = out + ((size_t)b * NPIX + bn * 256) * CCH + bi * 256;
    const float* Ib = inp + ((size_t)b * NPIX + bn * 256) * CCH + bi * 256;
#pragma unroll
    for (int m = 0; m < 8; ++m)
#pragma unroll
        for (int n = 0; n < 4; ++n)
#pragma unroll
            for (int r = 0; r < 4; ++r) {
                int nrow = wr * 128 + m * 16 + (lane >> 4) * 4 + r;
                int icol = wc * 64 + n * 16 + (lane & 15);
                size_t o = (size_t)nrow * CCH + icol;
                Ob[o] = g * acc[m][n][r] + Ib[o];
            }
}

// ---------------------------------------------------------------------------
extern "C" void kernel_launch(void* const* d_in, const int* in_sizes, int n_in,
                              void* d_out, int out_size, void* d_ws, size_t ws_size,
                              hipStream_t stream) {
    const float* inp   = (const float*)d_in[0];
    const float* gamma = (const float*)d_in[1];
    float* out = (float*)d_out;

    // workspace: Abf 64 MiB | AT 64 MiB | Sp 40 MiB | P 8 MiB  (~176.5 MiB)
    char* ws = (char*)d_ws;
    unsigned short* Abf = (unsigned short*)ws;
    unsigned short* AT  = (unsigned short*)(ws + (size_t)67108864);
    unsigned short* Sp  = (unsigned short*)(ws + (size_t)134217728);
    unsigned short* P   = (unsigned short*)(ws + (size_t)134217728 + 41943040);

    k_cvt<<<dim3(NPIX / 64, CCH / 64, BATCH), 256, 0, stream>>>(inp, Abf, AT);
    k_ata<<<dim3(NUT, NSPLIT, BATCH), 256, 0, stream>>>(AT, Sp);
    k_softmax<<<BATCH * 128, 256, 0, stream>>>(Sp, P);
    k_av<<<dim3(NPIX / 256, CCH / 256, BATCH), 512, 0, stream>>>(Abf, P, inp, gamma, out);
}